// Round 13
// baseline (106.710 us; speedup 1.0000x reference)
//
#include <hip/hip_runtime.h>
#include <hip/hip_bf16.h>

typedef float  f32x4  __attribute__((ext_vector_type(4)));
typedef short  bf16x8 __attribute__((ext_vector_type(8)));

#define NT      16384            // BATCH*SEQ tokens
#define NBLOCK  512              // 256-thr blocks; (256,2) + 80KB LDS -> 2 blocks/CU = 8 waves/CU
#define TPS     (NT / NBLOCK)    // 32 tokens per block (4-wave team, one token at a time)

__device__ __forceinline__ short f2bf(float x) {
  return (short)__builtin_bit_cast(unsigned short, __float2bfloat16(x));
}
__device__ __forceinline__ unsigned packbf2(float a, float b) {
  return (unsigned)(unsigned short)f2bf(a) | ((unsigned)(unsigned short)f2bf(b) << 16);
}

__device__ __forceinline__ void gload16(const float* gp, float* lp) {
  __builtin_amdgcn_global_load_lds((const __attribute__((address_space(1))) void*)gp,
                                   (__attribute__((address_space(3))) void*)lp,
                                   16, 0, 0);
}
__device__ __forceinline__ unsigned ldsaddr(const void* p) {
  return (unsigned)(uintptr_t)(const __attribute__((address_space(3))) void*)p;
}

// Half-stage: wave w stages 2 of its 4 chunks of one token's X (2 x 1KB).
// Same proven global-side XOR swizzle as R1/R5/R12 (0 measured conflicts).
__device__ __forceinline__ void stageHW(float* XB, const float* gbase, int w, int lane, int half) {
#pragma unroll
  for (int qq = 0; qq < 2; ++qq) {
    const int q = w * 4 + half * 2 + qq;
    const int i = q * 4 + (lane >> 4);
    const float* gp = gbase + i * 64 + (((lane & 15) ^ (i & 7)) << 2);
    gload16(gp, XB + q * 256);
  }
}
__device__ __forceinline__ void stageQW(float* XB, const float* gbase, int w, int lane) {
  stageHW(XB, gbase, w, lane, 0);
  stageHW(XB, gbase, w, lane, 1);
}

__global__ __launch_bounds__(256, 2)   // 2 waves/SIMD; cooperative split fits 128 VGPR (R12).
void kron_kernel(const float* __restrict__ x,
                 const float* __restrict__ A,
                 const float* __restrict__ Bm,
                 const float* __restrict__ bias,
                 float* __restrict__ out) {
  __shared__ float  xb[2][4096];            // 32KB X double-buffer (one token/team)
  __shared__ bf16x8 AT[1024];               // 16KB [s*8+ot*2+c][lane], sigma2 baked
  __shared__ bf16x8 BT[1024];               // 16KB [s*8+pt*2+jc][lane], sigma1
  __shared__ unsigned long long Ul[2048];   // 16KB U exchange: [s][pt][g][l15][slot0..3]

  const int tid  = threadIdx.x;
  const int lane = tid & 63;
  const int w    = tid >> 6;               // wave role: stage1 it=w, stage2 pt=w
  const int g    = lane >> 4;
  const int l15  = lane & 15;
  const int blk  = blockIdx.x;

  // ---- one-time: operand tables (4 rows per wave per table) ----
#pragma unroll
  for (int t = 0; t < 4; ++t) {                  // A: idx = s*8 + ot*2 + c
    const int idx = w * 4 + t;
    const int s = idx >> 3, ot = (idx & 7) >> 1, c = idx & 1;
    const int o = ot * 16 + l15;
    bf16x8 v;
#pragma unroll
    for (int e = 0; e < 8; ++e) {
      const int i = c * 32 + 4 * g + (e & 3) + 16 * (e >> 2);   // sigma2
      v[e] = f2bf(A[s * 4096 + o * 64 + i]);
    }
    AT[idx * 64 + lane] = v;
  }
#pragma unroll
  for (int t = 0; t < 4; ++t) {                  // B: idx = s*8 + pt*2 + jc
    const int idx = w * 4 + t;
    const int s = idx >> 3, pt = (idx & 7) >> 1, jc = idx & 1;
    const int p = pt * 16 + l15;
    bf16x8 v;
#pragma unroll
    for (int e = 0; e < 8; ++e)
      v[e] = f2bf(Bm[s * 4096 + p * 64 + (jc * 32 + 8 * g + e)]); // sigma1
    BT[idx * 64 + lane] = v;
  }

  // ---- bias slice (pt=w): 4 x f32x4 = 16 VGPR ----
  f32x4 bv[4];
#pragma unroll
  for (int ot = 0; ot < 4; ++ot)
    bv[ot] = *(const f32x4*)(bias + (ot * 16 + l15) * 64 + w * 16 + 4 * g);

  __syncthreads();   // tables visible; no gloads in flight yet, drain is free

  // ---- prologue: stage tokens 0,1 ----
  stageQW(&xb[0][0], x + ((size_t)blk << 12), w, lane);
  stageQW(&xb[1][0], x + ((size_t)(blk + NBLOCK) << 12), w, lane);
  asm volatile("s_waitcnt vmcnt(4)" ::: "memory");   // own X0 chunks done
  __builtin_amdgcn_s_barrier();                      // team X0 complete

  const unsigned wsw = (unsigned)(2 * ((l15 >> 2) & 1));   // U slot swizzle bit

  for (int k = 0; k < TPS; ++k) {
    // ---- 1. xf for it=w from xb[k&1] (asm ds_read, invisible to waitcnt pass) ----
    const unsigned ba   = ldsaddr(&xb[k & 1][0]);
    const unsigned base = ba + (unsigned)(w * 16 + l15) * 256u;
    const unsigned m    = (unsigned)(l15 & 7);
    f32x4 r0[2], r1[2];
#pragma unroll
    for (int jc = 0; jc < 2; ++jc) {
      const unsigned c0 = (unsigned)(8 * jc + 2 * g);
      asm volatile("ds_read_b128 %0, %1" : "=v"(r0[jc]) : "v"(base + ((c0 ^ m) << 4)) : "memory");
      asm volatile("ds_read_b128 %0, %1" : "=v"(r1[jc]) : "v"(base + (((c0 + 1u) ^ m) << 4)) : "memory");
    }
    asm volatile("s_waitcnt lgkmcnt(0)" ::: "memory");
    __builtin_amdgcn_sched_barrier(0);

    bf16x8 xf[2];
#pragma unroll
    for (int jc = 0; jc < 2; ++jc) {
      bf16x8 t;
      t[0]=f2bf(r0[jc][0]); t[1]=f2bf(r0[jc][1]); t[2]=f2bf(r0[jc][2]); t[3]=f2bf(r0[jc][3]);
      t[4]=f2bf(r1[jc][0]); t[5]=f2bf(r1[jc][1]); t[6]=f2bf(r1[jc][2]); t[7]=f2bf(r1[jc][3]);
      xf[jc] = t;
    }

    // ---- 2. stage 1 (it=w, all pt, both s): U tiles -> LDS exchange ----
#pragma unroll
    for (int s = 0; s < 2; ++s) {
#pragma unroll
      for (int pt = 0; pt < 4; ++pt) {
        f32x4 a1 = (f32x4){0.f, 0.f, 0.f, 0.f};
#pragma unroll
        for (int jc = 0; jc < 2; ++jc)
          a1 = __builtin_amdgcn_mfma_f32_16x16x32_bf16(
              xf[jc], BT[(s * 8 + pt * 2 + jc) * 64 + lane], a1, 0, 0, 0);
        // lane holds U[w*16+4g+r][pt*16+l15], r=0..3 -> one 8B slot
        const unsigned lo = packbf2(a1[0], a1[1]);
        const unsigned hi = packbf2(a1[2], a1[3]);
        Ul[((((s * 4 + pt) * 4 + g) * 16 + l15) << 2) + ((unsigned)w ^ wsw)] =
            ((unsigned long long)hi << 32) | lo;
      }
    }

    // ---- 3. barrier 1: U visible (lgkmcnt only; vmcnt prefetch stays in flight) ----
    asm volatile("s_waitcnt lgkmcnt(0)" ::: "memory");
    __builtin_amdgcn_sched_barrier(0);
    __builtin_amdgcn_s_barrier();

    const float* xp2 = x + ((size_t)(blk + (k + 2) * NBLOCK) << 12);

    // ---- 4. A: FIRST half of X(k+2) prefetch (port-feed point 1) ----
    if (k + 2 < TPS)
      stageHW(&xb[k & 1][0], xp2, w, lane, 0);

    // ---- 5. stage 2 (pt=w), ot-outer so each acc[ot] completes independently
    // and its store issues immediately -> 4 interleaved store points ----
    bf16x8 uf[2][2];
#pragma unroll
    for (int s = 0; s < 2; ++s)
#pragma unroll
      for (int c = 0; c < 2; ++c) {
        const unsigned q2 = (unsigned)((l15 >> 2) & 1);
        uf[s][c] = *reinterpret_cast<const bf16x8*>(
            &Ul[((((s * 4 + w) * 4 + g) * 16 + l15) << 2) + 2u * ((unsigned)c ^ q2)]);
      }

    float* ob = out + ((size_t)(blk + k * NBLOCK) << 12);
#pragma unroll
    for (int ot = 0; ot < 4; ++ot) {
      f32x4 acc = bv[ot];
#pragma unroll
      for (int s = 0; s < 2; ++s)
#pragma unroll
        for (int c = 0; c < 2; ++c)
          acc = __builtin_amdgcn_mfma_f32_16x16x32_bf16(
              uf[s][c], AT[(s * 8 + ot * 2 + c) * 64 + lane], acc, 0, 0, 0);
      *(f32x4*)(ob + (ot * 16 + l15) * 64 + w * 16 + 4 * g) = acc;   // store point
    }

    // ---- 6. C: SECOND half of X(k+2) prefetch (port-feed point late) ----
    if (k + 2 < TPS)
      stageHW(&xb[k & 1][0], xp2, w, lane, 1);

    // ---- 7. barrier 2: counted vmcnt. Per-wave in-order stream per token:
    // A(2 gl) | St(4) | C(2 gl). At this wait we need gl(k+1)=A_{k-1}+C_{k-1}
    // complete: newer ops = A_k(2)+St_k(4)+C_k(2) = 8 -> vmcnt(8).
    // Tail (no A_k/C_k): newer = St_k(4) -> vmcnt(4).
    // lgkmcnt(0): uf reads serviced before next token's U overwrite.
    if (k + 2 < TPS) asm volatile("s_waitcnt vmcnt(8) lgkmcnt(0)" ::: "memory");
    else             asm volatile("s_waitcnt vmcnt(4) lgkmcnt(0)" ::: "memory");
    __builtin_amdgcn_sched_barrier(0);
    __builtin_amdgcn_s_barrier();
  }
}

extern "C" void kernel_launch(void* const* d_in, const int* in_sizes, int n_in,
                              void* d_out, int out_size, void* d_ws, size_t ws_size,
                              hipStream_t stream) {
  const float* x    = (const float*)d_in[0];
  const float* A    = (const float*)d_in[1];
  const float* B    = (const float*)d_in[2];
  const float* bias = (const float*)d_in[3];
  float* out        = (float*)d_out;
  kron_kernel<<<dim3(NBLOCK), dim3(256), 0, stream>>>(x, A, B, bias, out);
}